// Round 1
// baseline (796.511 us; speedup 1.0000x reference)
//
#include <hip/hip_runtime.h>

typedef unsigned int u32;
typedef unsigned short u16;
typedef __attribute__((ext_vector_type(8))) short short8;
typedef __attribute__((ext_vector_type(4))) float f32x4;

#define DD 128
#define RREL 8
#define SCAN_CHUNK 4096

static __device__ __forceinline__ u16 f2bf(float f) {
  u32 u = __builtin_bit_cast(u32, f);
  u32 r = (u + 0x7fffu + ((u >> 16) & 1u)) >> 16;
  return (u16)r;
}
static __device__ __forceinline__ float bflo(u32 v) { return __builtin_bit_cast(float, v << 16); }
static __device__ __forceinline__ float bfhi(u32 v) { return __builtin_bit_cast(float, v & 0xffff0000u); }

// ---- convert W (and root) to bf16, transposed: wt[slot][col][k] = W[slot][k][col]
__global__ __launch_bounds__(256) void k_convw(const float* __restrict__ W,
                                               const float* __restrict__ root,
                                               u16* __restrict__ wt) {
  int t = blockIdx.x * 256 + threadIdx.x;
  if (t < 2 * RREL * DD * DD) {            // W: [2][8][128][128]
    int slot = t >> 14;                    // l*8+r
    int rem = t & 16383;
    int col = rem >> 7, kk = rem & 127;
    wt[(size_t)slot * 16384 + col * 128 + kk] = f2bf(W[(size_t)slot * 16384 + kk * 128 + col]);
  } else if (t < 2 * RREL * DD * DD + 2 * DD * DD) {
    int t2 = t - 2 * RREL * DD * DD;       // root: [2][128][128]
    int l = t2 >> 14;
    int rem = t2 & 16383;
    int col = rem >> 7, kk = rem & 127;
    wt[(size_t)(16 + l) * 16384 + col * 128 + kk] = f2bf(root[(size_t)l * 16384 + kk * 128 + col]);
  }
}

// ---- h0 = bf16(emb[x])  packed 2 bf16 / u32, [N][64] u32 view as uint4 [N][16]
__global__ __launch_bounds__(256) void k_gather(const int* __restrict__ x,
                                                const float* __restrict__ emb,
                                                uint4* __restrict__ hA, int N) {
  int t = blockIdx.x * 256 + threadIdx.x;
  if (t >= N * 16) return;
  int node = t >> 4, part = t & 15;
  const float4* e4 = (const float4*)(emb + (size_t)x[node] * 128 + part * 8);
  float4 f0 = e4[0], f1 = e4[1];
  uint4 u;
  u.x = (u32)f2bf(f0.x) | ((u32)f2bf(f0.y) << 16);
  u.y = (u32)f2bf(f0.z) | ((u32)f2bf(f0.w) << 16);
  u.z = (u32)f2bf(f1.x) | ((u32)f2bf(f1.y) << 16);
  u.w = (u32)f2bf(f1.z) | ((u32)f2bf(f1.w) << 16);
  hA[t] = u;
}

// ---- histogram over segments seg = dst*8 + etype
__global__ __launch_bounds__(256) void k_hist(const int* __restrict__ ei,
                                              const int* __restrict__ et,
                                              int* __restrict__ cnt, int E) {
  int e = blockIdx.x * 256 + threadIdx.x;
  if (e >= E) return;
  int dst = ei[E + e];
  atomicAdd(&cnt[dst * 8 + et[e]], 1);
}

__global__ __launch_bounds__(256) void k_scan_reduce(const int* __restrict__ cnt,
                                                     int* __restrict__ blksum, int nseg) {
  __shared__ int s[256];
  int b = blockIdx.x, t = threadIdx.x;
  int base = b * SCAN_CHUNK;
  int sum = 0;
  for (int i = 0; i < 16; ++i) {
    int idx = base + i * 256 + t;
    if (idx < nseg) sum += cnt[idx];
  }
  s[t] = sum;
  __syncthreads();
  for (int st = 128; st > 0; st >>= 1) {
    if (t < st) s[t] += s[t + st];
    __syncthreads();
  }
  if (t == 0) blksum[b] = s[0];
}

__global__ void k_scan_top(int* __restrict__ blksum, int nblk, int* __restrict__ off,
                           int nseg, int E) {
  if (threadIdx.x == 0 && blockIdx.x == 0) {
    int run = 0;
    for (int b = 0; b < nblk; ++b) { int v = blksum[b]; blksum[b] = run; run += v; }
    off[nseg] = E;
  }
}

__global__ __launch_bounds__(256) void k_scan_write(const int* __restrict__ cnt,
                                                    const int* __restrict__ blksum,
                                                    int* __restrict__ off, int nseg) {
  __shared__ int s[256];
  int b = blockIdx.x, t = threadIdx.x;
  int base = b * SCAN_CHUNK + t * 16;
  int v[16];
  int sum = 0;
#pragma unroll
  for (int i = 0; i < 16; ++i) {
    int idx = base + i;
    v[i] = (idx < nseg) ? cnt[idx] : 0;
    sum += v[i];
  }
  s[t] = sum;
  __syncthreads();
  for (int st = 1; st < 256; st <<= 1) {
    int add = (t >= st) ? s[t - st] : 0;
    __syncthreads();
    s[t] += add;
    __syncthreads();
  }
  int run = blksum[b] + s[t] - sum;  // exclusive base for this thread's chunk
#pragma unroll
  for (int i = 0; i < 16; ++i) {
    int idx = base + i;
    if (idx < nseg) off[idx] = run;
    run += v[i];
  }
}

__global__ __launch_bounds__(256) void k_scatter(const int* __restrict__ ei,
                                                 const int* __restrict__ et,
                                                 const int* __restrict__ off,
                                                 int* __restrict__ fill,
                                                 int* __restrict__ sorted, int E) {
  int e = blockIdx.x * 256 + threadIdx.x;
  if (e >= E) return;
  int src = ei[e], dst = ei[E + e];
  int seg = dst * 8 + et[e];
  int pos = off[seg] + atomicAdd(&fill[seg], 1);
  sorted[pos] = src;
}

// ---- GEMM: out[row][col] = sum_k hbf[row][k] * Wt[widx][col][k]   (Wt is pre-transposed)
// F32OUT: write f32 + bias into ofp (root path). else write bf16 into obf + rb*M*128.
template <bool F32OUT>
__global__ __launch_bounds__(256) void k_gemm(const u16* __restrict__ hbf,
                                              const u16* __restrict__ wt, int widx0,
                                              u16* __restrict__ obf, float* __restrict__ ofp,
                                              const float* __restrict__ bias, int M) {
  __shared__ uint4 ldsW[2048];  // 32KB, W^T [col][k] bf16, XOR-swizzled 16B blocks
  int rb = blockIdx.y;
  const uint4* wsrc = (const uint4*)(wt + (size_t)(widx0 + rb) * 16384);
#pragma unroll
  for (int i = 0; i < 8; ++i) {
    int cid = i * 256 + threadIdx.x;   // 16B chunk id, 2048 total
    uint4 v = wsrc[cid];
    int col = cid >> 4;
    int kb = (cid & 15) << 4;
    ldsW[col * 16 + ((kb ^ ((col & 7) << 4)) >> 4)] = v;
  }
  __syncthreads();
  int wave = threadIdx.x >> 6, lane = threadIdx.x & 63;
  int arow = blockIdx.x * 64 + wave * 16 + (lane & 15);
  int arc = arow < M ? arow : M - 1;
  int klane = (lane >> 4) << 3;
  f32x4 acc[8];
#pragma unroll
  for (int c = 0; c < 8; ++c) acc[c] = (f32x4)0.f;
#pragma unroll
  for (int kc = 0; kc < 4; ++kc) {
    short8 a = *(const short8*)(hbf + (size_t)arc * 128 + kc * 32 + klane);
    int kbyte = (kc * 32 + klane) * 2;
#pragma unroll
    for (int c = 0; c < 8; ++c) {
      int col = c * 16 + (lane & 15);
      const short8* bp =
          (const short8*)((const char*)ldsW + col * 256 + (kbyte ^ ((col & 7) << 4)));
      acc[c] = __builtin_amdgcn_mfma_f32_16x16x32_bf16(a, *bp, acc[c], 0, 0, 0);
    }
  }
  int crow0 = blockIdx.x * 64 + wave * 16 + ((lane >> 4) << 2);
  int ccol = lane & 15;
  if (F32OUT) {
#pragma unroll
    for (int c = 0; c < 8; ++c) {
      int col = c * 16 + ccol;
      float bv = bias[col];
#pragma unroll
      for (int i = 0; i < 4; ++i) {
        int row = crow0 + i;
        if (row < M) ofp[(size_t)row * 128 + col] = acc[c][i] + bv;
      }
    }
  } else {
    u16* out = obf + (size_t)rb * M * 128;
#pragma unroll
    for (int c = 0; c < 8; ++c) {
      int col = c * 16 + ccol;
#pragma unroll
      for (int i = 0; i < 4; ++i) {
        int row = crow0 + i;
        if (row < M) out[(size_t)row * 128 + col] = f2bf(acc[c][i]);
      }
    }
  }
}

// ---- aggregation: one wave per dst; acc(f32x2 per lane over 128 feats) starts from d_out
// (root+bias), adds mean-normalized xW[etype][src] rows; last pass applies relu and stores.
__global__ __launch_bounds__(256) void k_agg(const int* __restrict__ off,
                                             const int* __restrict__ sorted,
                                             const u32* __restrict__ xw,  // [rc][N][64]
                                             float* __restrict__ dout,    // [N][128] accum
                                             u32* __restrict__ hnext,     // bf16 out or null
                                             int N, int r0, int r1, int lastpass,
                                             int writef32) {
  int wave = threadIdx.x >> 6, lane = threadIdx.x & 63;
  int dst = blockIdx.x * 4 + wave;
  if (dst >= N) return;
  float2* dp = (float2*)dout;
  float2 acc = dp[(size_t)dst * 64 + lane];
  for (int r = r0; r < r1; ++r) {
    int s = off[dst * 8 + r], e = off[dst * 8 + r + 1];
    if (e > s) {
      float norm = 1.0f / (float)(e - s);
      const u32* base = xw + ((size_t)(r - r0) * N) * 64 + lane;
      for (int j = s; j < e; ++j) {
        int src = sorted[j];
        u32 v = base[(size_t)src * 64];
        acc.x += norm * bflo(v);
        acc.y += norm * bfhi(v);
      }
    }
  }
  if (lastpass) {
    acc.x = fmaxf(acc.x, 0.f);
    acc.y = fmaxf(acc.y, 0.f);
    if (writef32) dp[(size_t)dst * 64 + lane] = acc;
    else hnext[(size_t)dst * 64 + lane] = (u32)f2bf(acc.x) | ((u32)f2bf(acc.y) << 16);
  } else {
    dp[(size_t)dst * 64 + lane] = acc;
  }
}

extern "C" void kernel_launch(void* const* d_in, const int* in_sizes, int n_in,
                              void* d_out, int out_size, void* d_ws, size_t ws_size,
                              hipStream_t stream) {
  const int* x = (const int*)d_in[0];
  const int* ei = (const int*)d_in[1];
  const int* et = (const int*)d_in[2];
  const float* emb = (const float*)d_in[3];
  const float* W = (const float*)d_in[4];
  const float* root = (const float*)d_in[5];
  const float* bias = (const float*)d_in[6];

  const int N = in_sizes[0];
  const int E = in_sizes[2];
  const size_t NSEG = (size_t)N * RREL;

  // ---- workspace layout
  size_t o = 0;
  auto al = [&](size_t b) { size_t r = o; o = (o + b + 255) & ~(size_t)255; return r; };
  size_t off_o = al((NSEG + 1) * 4);
  size_t cnt_o = al(NSEG * 4);
  size_t fill_o = al(NSEG * 4);
  size_t sorted_o = al((size_t)E * 4);
  size_t blk_o = al(4096);
  size_t wt_o = al((size_t)18 * 16384 * 2);
  size_t hA_o = al((size_t)N * 128 * 2);
  size_t hB_o = al((size_t)N * 128 * 2);
  size_t base = o;
  int RC = 1;
  {
    const int cand[4] = {8, 4, 2, 1};
    for (int i = 0; i < 4; ++i) {
      if (base + (size_t)cand[i] * N * 128 * 2 <= ws_size) { RC = cand[i]; break; }
    }
  }
  size_t xw_o = al((size_t)RC * N * 128 * 2);
  (void)xw_o;

  char* ws = (char*)d_ws;
  int* off = (int*)(ws + off_o);
  int* cnt = (int*)(ws + cnt_o);
  int* fill = (int*)(ws + fill_o);
  int* sorted = (int*)(ws + sorted_o);
  int* blks = (int*)(ws + blk_o);
  u16* wt = (u16*)(ws + wt_o);
  u16* hA = (u16*)(ws + hA_o);
  u16* hB = (u16*)(ws + hB_o);
  u16* xw = (u16*)(ws + xw_o);
  float* outf = (float*)d_out;

  // ---- one-time prep
  k_convw<<<(2 * RREL * DD * DD + 2 * DD * DD + 255) / 256, 256, 0, stream>>>(W, root, wt);
  k_gather<<<(N * 16 + 255) / 256, 256, 0, stream>>>(x, emb, (uint4*)hA, N);
  hipMemsetAsync(cnt, 0, NSEG * 4, stream);
  hipMemsetAsync(fill, 0, NSEG * 4, stream);
  k_hist<<<(E + 255) / 256, 256, 0, stream>>>(ei, et, cnt, E);
  int nblk = (int)((NSEG + SCAN_CHUNK - 1) / SCAN_CHUNK);
  k_scan_reduce<<<nblk, 256, 0, stream>>>(cnt, blks, (int)NSEG);
  k_scan_top<<<1, 64, 0, stream>>>(blks, nblk, off, (int)NSEG, E);
  k_scan_write<<<nblk, 256, 0, stream>>>(cnt, blks, off, (int)NSEG);
  k_scatter<<<(E + 255) / 256, 256, 0, stream>>>(ei, et, off, fill, sorted, E);

  // ---- layers
  int gx = (N + 63) / 64;
  for (int l = 0; l < 2; ++l) {
    const u16* hin = l ? hB : hA;
    // root term + bias -> d_out (f32 accumulator)
    k_gemm<true><<<dim3(gx, 1), 256, 0, stream>>>(hin, wt, 16 + l, nullptr, outf,
                                                  bias + (size_t)l * 128, N);
    int passes = (RREL + RC - 1) / RC;
    for (int p = 0; p < passes; ++p) {
      int r0 = p * RC, r1 = r0 + RC;
      if (r1 > RREL) r1 = RREL;
      k_gemm<false><<<dim3(gx, r1 - r0), 256, 0, stream>>>(hin, wt, l * RREL + r0, xw,
                                                           nullptr, nullptr, N);
      int last = (r1 == RREL) ? 1 : 0;
      k_agg<<<(N + 3) / 4, 256, 0, stream>>>(off, sorted, (const u32*)xw, outf,
                                             (l == 0) ? (u32*)hB : nullptr, N, r0, r1,
                                             last, l == 1 ? 1 : 0);
    }
  }
}

// Round 2
// 603.009 us; speedup vs baseline: 1.3209x; 1.3209x over previous
//
#include <hip/hip_runtime.h>

typedef unsigned int u32;
typedef unsigned short u16;
typedef __attribute__((ext_vector_type(8))) short short8;
typedef __attribute__((ext_vector_type(4))) float f32x4;

#define DD 128
#define RREL 8
#define KCAT 1152  // 128 (h/root) + 8*128 (per-relation aggregated means)
#define SCAN_CHUNK 4096

static __device__ __forceinline__ u16 f2bf(float f) {
  u32 u = __builtin_bit_cast(u32, f);
  u32 r = (u + 0x7fffu + ((u >> 16) & 1u)) >> 16;
  return (u16)r;
}
static __device__ __forceinline__ float bflo(u32 v) { return __builtin_bit_cast(float, v << 16); }
static __device__ __forceinline__ float bfhi(u32 v) { return __builtin_bit_cast(float, v & 0xffff0000u); }

// ---- build concatenated transposed weights: wt[l][col][k], k = [root(128) | W_0..W_7]
__global__ __launch_bounds__(256) void k_convw(const float* __restrict__ W,
                                               const float* __restrict__ root,
                                               u16* __restrict__ wt) {
  int t = blockIdx.x * 256 + threadIdx.x;
  if (t >= 2 * DD * KCAT) return;
  int l = t / (DD * KCAT);
  int rem = t - l * DD * KCAT;
  int col = rem / KCAT;
  int k = rem - col * KCAT;
  float v;
  if (k < DD) {
    v = root[(size_t)l * DD * DD + k * DD + col];
  } else {
    int r = (k - DD) >> 7, kk = (k - DD) & 127;
    v = W[(size_t)(l * RREL + r) * DD * DD + kk * DD + col];
  }
  wt[(size_t)l * DD * KCAT + col * KCAT + k] = f2bf(v);
}

// ---- h0 = bf16(emb[x]) into Acat[node][0:128]
__global__ __launch_bounds__(256) void k_gather(const int* __restrict__ x,
                                                const float* __restrict__ emb,
                                                u16* __restrict__ acat, int N) {
  int t = blockIdx.x * 256 + threadIdx.x;
  if (t >= N * 16) return;
  int node = t >> 4, part = t & 15;
  const float4* e4 = (const float4*)(emb + (size_t)x[node] * DD + part * 8);
  float4 f0 = e4[0], f1 = e4[1];
  uint4 u;
  u.x = (u32)f2bf(f0.x) | ((u32)f2bf(f0.y) << 16);
  u.y = (u32)f2bf(f0.z) | ((u32)f2bf(f0.w) << 16);
  u.z = (u32)f2bf(f1.x) | ((u32)f2bf(f1.y) << 16);
  u.w = (u32)f2bf(f1.z) | ((u32)f2bf(f1.w) << 16);
  *(uint4*)(acat + (size_t)node * KCAT + part * 8) = u;
}

// ---- histogram over segments seg = dst*8 + etype
__global__ __launch_bounds__(256) void k_hist(const int* __restrict__ ei,
                                              const int* __restrict__ et,
                                              int* __restrict__ cnt, int E) {
  int e = blockIdx.x * 256 + threadIdx.x;
  if (e >= E) return;
  int dst = ei[E + e];
  atomicAdd(&cnt[dst * 8 + et[e]], 1);
}

__global__ __launch_bounds__(256) void k_scan_reduce(const int* __restrict__ cnt,
                                                     int* __restrict__ blksum, int nseg) {
  __shared__ int s[256];
  int b = blockIdx.x, t = threadIdx.x;
  int base = b * SCAN_CHUNK;
  int sum = 0;
  for (int i = 0; i < 16; ++i) {
    int idx = base + i * 256 + t;
    if (idx < nseg) sum += cnt[idx];
  }
  s[t] = sum;
  __syncthreads();
  for (int st = 128; st > 0; st >>= 1) {
    if (t < st) s[t] += s[t + st];
    __syncthreads();
  }
  if (t == 0) blksum[b] = s[0];
}

__global__ void k_scan_top(int* __restrict__ blksum, int nblk, int* __restrict__ off,
                           int nseg, int E) {
  if (threadIdx.x == 0 && blockIdx.x == 0) {
    int run = 0;
    for (int b = 0; b < nblk; ++b) { int v = blksum[b]; blksum[b] = run; run += v; }
    off[nseg] = E;
  }
}

__global__ __launch_bounds__(256) void k_scan_write(const int* __restrict__ cnt,
                                                    const int* __restrict__ blksum,
                                                    int* __restrict__ off, int nseg) {
  __shared__ int s[256];
  int b = blockIdx.x, t = threadIdx.x;
  int base = b * SCAN_CHUNK + t * 16;
  int v[16];
  int sum = 0;
#pragma unroll
  for (int i = 0; i < 16; ++i) {
    int idx = base + i;
    v[i] = (idx < nseg) ? cnt[idx] : 0;
    sum += v[i];
  }
  s[t] = sum;
  __syncthreads();
  for (int st = 1; st < 256; st <<= 1) {
    int add = (t >= st) ? s[t - st] : 0;
    __syncthreads();
    s[t] += add;
    __syncthreads();
  }
  int run = blksum[b] + s[t] - sum;
#pragma unroll
  for (int i = 0; i < 16; ++i) {
    int idx = base + i;
    if (idx < nseg) off[idx] = run;
    run += v[i];
  }
}

__global__ __launch_bounds__(256) void k_scatter(const int* __restrict__ ei,
                                                 const int* __restrict__ et,
                                                 const int* __restrict__ off,
                                                 int* __restrict__ fill,
                                                 int* __restrict__ sorted, int E) {
  int e = blockIdx.x * 256 + threadIdx.x;
  if (e >= E) return;
  int src = ei[e], dst = ei[E + e];
  int seg = dst * 8 + et[e];
  int pos = off[seg] + atomicAdd(&fill[seg], 1);
  sorted[pos] = src;
}

// ---- aggregation: mean of h[src] per (dst,rel) segment -> Acat[dst][128 + r*128 : +128]
// 4 segments per wave: 16 lanes per segment, each lane owns 16B (8 bf16) of the row.
// Empty segments write zeros (required: Am region starts poisoned).
__global__ __launch_bounds__(256) void k_agg(const int* __restrict__ off,
                                             const int* __restrict__ sorted,
                                             u16* acat, int nseg) {
  int wave = threadIdx.x >> 6, lane = threadIdx.x & 63;
  int sub = lane >> 4, quad = lane & 15;
  int seg = blockIdx.x * 16 + wave * 4 + sub;
  if (seg >= nseg) return;
  int s = off[seg], e = off[seg + 1];
  float a0 = 0.f, a1 = 0.f, a2 = 0.f, a3 = 0.f, a4 = 0.f, a5 = 0.f, a6 = 0.f, a7 = 0.f;
  for (int j = s; j < e; ++j) {
    int src = sorted[j];
    uint4 v = *(const uint4*)(acat + (size_t)src * KCAT + quad * 8);
    a0 += bflo(v.x); a1 += bfhi(v.x);
    a2 += bflo(v.y); a3 += bfhi(v.y);
    a4 += bflo(v.z); a5 += bfhi(v.z);
    a6 += bflo(v.w); a7 += bfhi(v.w);
  }
  float norm = (e > s) ? 1.0f / (float)(e - s) : 0.f;
  uint4 w;
  w.x = (u32)f2bf(a0 * norm) | ((u32)f2bf(a1 * norm) << 16);
  w.y = (u32)f2bf(a2 * norm) | ((u32)f2bf(a3 * norm) << 16);
  w.z = (u32)f2bf(a4 * norm) | ((u32)f2bf(a5 * norm) << 16);
  w.w = (u32)f2bf(a6 * norm) | ((u32)f2bf(a7 * norm) << 16);
  int dst = seg >> 3, r = seg & 7;
  *(uint4*)(acat + (size_t)dst * KCAT + DD + r * DD + quad * 8) = w;
}

// ---- fused GEMM: out[row] = relu( Acat[row][0:1152] @ Wcat(1152x128) + bias )
// LAST=false: write bf16 h_next into Acat[row][0:128] (in-place safe: each block only
// reads/writes its own rows, and reads of [0:128] happen only in k-tile 0 before epilogue).
// LAST=true: write f32 to d_out.
template <bool LAST>
__global__ __launch_bounds__(256) void k_gemm(u16* acat, const u16* __restrict__ wt,
                                              const float* __restrict__ bias,
                                              float* __restrict__ dout, int M) {
  __shared__ uint4 ldsB[2048];  // 32KB: one 128-wide k-tile of B^T, XOR-swizzled 16B units
  int tid = threadIdx.x, wave = tid >> 6, lane = tid & 63;
  int rowbase = blockIdx.x * 64 + wave * 16;
  int arow = rowbase + (lane & 15);
  int arc = arow < M ? arow : M - 1;
  int klane = (lane >> 4) << 3;
  f32x4 acc[8];
#pragma unroll
  for (int c = 0; c < 8; ++c) acc[c] = (f32x4)0.f;
  for (int kt = 0; kt < 9; ++kt) {
    __syncthreads();
#pragma unroll
    for (int i = 0; i < 8; ++i) {
      int cid = i * 256 + tid;  // 2048 16B chunks: col = cid>>4, cb = cid&15
      int col = cid >> 4, cb = cid & 15;
      uint4 v = *(const uint4*)(wt + (size_t)col * KCAT + kt * DD + cb * 8);
      ldsB[col * 16 + (cb ^ (col & 7))] = v;
    }
    __syncthreads();
#pragma unroll
    for (int kc = 0; kc < 4; ++kc) {
      short8 a = *(const short8*)(acat + (size_t)arc * KCAT + kt * DD + kc * 32 + klane);
      int chunk = kc * 4 + (lane >> 4);
#pragma unroll
      for (int c = 0; c < 8; ++c) {
        int col = c * 16 + (lane & 15);
        const short8* bp = (const short8*)&ldsB[col * 16 + (chunk ^ (col & 7))];
        acc[c] = __builtin_amdgcn_mfma_f32_16x16x32_bf16(a, *bp, acc[c], 0, 0, 0);
      }
    }
  }
  int crow0 = rowbase + ((lane >> 4) << 2);
  int ccol = lane & 15;
#pragma unroll
  for (int c = 0; c < 8; ++c) {
    int col = c * 16 + ccol;
    float bv = bias[col];
#pragma unroll
    for (int i = 0; i < 4; ++i) {
      int row = crow0 + i;
      if (row < M) {
        float v = fmaxf(acc[c][i] + bv, 0.f);
        if (LAST) dout[(size_t)row * DD + col] = v;
        else acat[(size_t)row * KCAT + col] = f2bf(v);
      }
    }
  }
}

extern "C" void kernel_launch(void* const* d_in, const int* in_sizes, int n_in,
                              void* d_out, int out_size, void* d_ws, size_t ws_size,
                              hipStream_t stream) {
  const int* x = (const int*)d_in[0];
  const int* ei = (const int*)d_in[1];
  const int* et = (const int*)d_in[2];
  const float* emb = (const float*)d_in[3];
  const float* W = (const float*)d_in[4];
  const float* root = (const float*)d_in[5];
  const float* bias = (const float*)d_in[6];

  const int N = in_sizes[0];
  const int E = in_sizes[2];
  const int NSEG = N * RREL;

  size_t o = 0;
  auto al = [&](size_t b) { size_t r = o; o = (o + b + 255) & ~(size_t)255; return r; };
  size_t off_o = al(((size_t)NSEG + 1) * 4);
  size_t cnt_o = al((size_t)NSEG * 4);
  size_t fill_o = al((size_t)NSEG * 4);
  size_t sorted_o = al((size_t)E * 4);
  size_t blk_o = al(4096);
  size_t wt_o = al((size_t)2 * DD * KCAT * 2);
  size_t acat_o = al((size_t)N * KCAT * 2);
  (void)acat_o;

  char* ws = (char*)d_ws;
  int* off = (int*)(ws + off_o);
  int* cnt = (int*)(ws + cnt_o);
  int* fill = (int*)(ws + fill_o);
  int* sorted = (int*)(ws + sorted_o);
  int* blks = (int*)(ws + blk_o);
  u16* wt = (u16*)(ws + wt_o);
  u16* acat = (u16*)(ws + acat_o);
  float* outf = (float*)d_out;

  // ---- prep
  k_convw<<<(2 * DD * KCAT + 255) / 256, 256, 0, stream>>>(W, root, wt);
  k_gather<<<(N * 16 + 255) / 256, 256, 0, stream>>>(x, emb, acat, N);
  hipMemsetAsync(cnt, 0, (size_t)NSEG * 4, stream);
  hipMemsetAsync(fill, 0, (size_t)NSEG * 4, stream);
  k_hist<<<(E + 255) / 256, 256, 0, stream>>>(ei, et, cnt, E);
  int nblk = (NSEG + SCAN_CHUNK - 1) / SCAN_CHUNK;
  k_scan_reduce<<<nblk, 256, 0, stream>>>(cnt, blks, NSEG);
  k_scan_top<<<1, 64, 0, stream>>>(blks, nblk, off, NSEG, E);
  k_scan_write<<<nblk, 256, 0, stream>>>(cnt, blks, off, NSEG);
  k_scatter<<<(E + 255) / 256, 256, 0, stream>>>(ei, et, off, fill, sorted, E);

  // ---- layers: agg (mean into Acat) then fused GEMM (root+rels+bias+relu)
  int gx = (N + 63) / 64;
  k_agg<<<(NSEG + 15) / 16, 256, 0, stream>>>(off, sorted, acat, NSEG);
  k_gemm<false><<<gx, 256, 0, stream>>>(acat, wt, bias, nullptr, N);
  k_agg<<<(NSEG + 15) / 16, 256, 0, stream>>>(off, sorted, acat, NSEG);
  k_gemm<true><<<gx, 256, 0, stream>>>(acat, wt + (size_t)DD * KCAT, bias + DD, outf, N);
}

// Round 3
// 512.500 us; speedup vs baseline: 1.5542x; 1.1766x over previous
//
#include <hip/hip_runtime.h>

typedef unsigned int u32;
typedef unsigned short u16;
typedef __attribute__((ext_vector_type(8))) short short8;
typedef __attribute__((ext_vector_type(4))) float f32x4;

#define DD 128
#define RREL 8
#define KCAT 1152  // 128 (h/root) + 8*128 (per-relation aggregated means)
#define NKT 9      // KCAT / 128 k-tiles
#define SCAN_CHUNK 4096

static __device__ __forceinline__ u16 f2bf(float f) {
  u32 u = __builtin_bit_cast(u32, f);
  u32 r = (u + 0x7fffu + ((u >> 16) & 1u)) >> 16;
  return (u16)r;
}
static __device__ __forceinline__ float bflo(u32 v) { return __builtin_bit_cast(float, v << 16); }
static __device__ __forceinline__ float bfhi(u32 v) { return __builtin_bit_cast(float, v & 0xffff0000u); }

// ---- build pre-swizzled transposed weights for linear global_load_lds staging.
// wt[l][kt][pos] (16B chunks): pos = col*16 + cbx holds chunk (col, cb=cbx^(col&7)),
// chunk (col,cb) = 8 bf16 of column `col` at k = kt*128 + cb*8 .. +8, k-space = [root | W0..W7].
__global__ __launch_bounds__(256) void k_convw(const float* __restrict__ W,
                                               const float* __restrict__ root,
                                               uint4* __restrict__ wt) {
  int t = blockIdx.x * 256 + threadIdx.x;
  if (t >= 2 * NKT * 2048) return;
  int l = t / (NKT * 2048);
  int rem = t - l * (NKT * 2048);
  int kt = rem >> 11;
  int pos = rem & 2047;
  int col = pos >> 4;
  int cbx = pos & 15;
  int cb = cbx ^ (col & 7);
  int k0 = kt * DD + cb * 8;
  u16 vals[8];
#pragma unroll
  for (int i = 0; i < 8; ++i) {
    int k = k0 + i;
    float v;
    if (k < DD) {
      v = root[(size_t)l * DD * DD + k * DD + col];
    } else {
      int km = k - DD;
      v = W[((size_t)l * RREL + (km >> 7)) * DD * DD + (size_t)(km & 127) * DD + col];
    }
    vals[i] = f2bf(v);
  }
  wt[t] = *(uint4*)vals;
}

// ---- h0 = bf16(emb[x]) into Acat[node][0:128]
__global__ __launch_bounds__(256) void k_gather(const int* __restrict__ x,
                                                const float* __restrict__ emb,
                                                u16* __restrict__ acat, int N) {
  int t = blockIdx.x * 256 + threadIdx.x;
  if (t >= N * 16) return;
  int node = t >> 4, part = t & 15;
  const float4* e4 = (const float4*)(emb + (size_t)x[node] * DD + part * 8);
  float4 f0 = e4[0], f1 = e4[1];
  uint4 u;
  u.x = (u32)f2bf(f0.x) | ((u32)f2bf(f0.y) << 16);
  u.y = (u32)f2bf(f0.z) | ((u32)f2bf(f0.w) << 16);
  u.z = (u32)f2bf(f1.x) | ((u32)f2bf(f1.y) << 16);
  u.w = (u32)f2bf(f1.z) | ((u32)f2bf(f1.w) << 16);
  *(uint4*)(acat + (size_t)node * KCAT + part * 8) = u;
}

// ---- histogram over segments seg = dst*8 + etype
__global__ __launch_bounds__(256) void k_hist(const int* __restrict__ ei,
                                              const int* __restrict__ et,
                                              int* __restrict__ cnt, int E) {
  int e = blockIdx.x * 256 + threadIdx.x;
  if (e >= E) return;
  int dst = ei[E + e];
  atomicAdd(&cnt[dst * 8 + et[e]], 1);
}

__global__ __launch_bounds__(256) void k_scan_reduce(const int* __restrict__ cnt,
                                                     int* __restrict__ blksum, int nseg) {
  __shared__ int s[256];
  int b = blockIdx.x, t = threadIdx.x;
  int base = b * SCAN_CHUNK;
  int sum = 0;
  for (int i = 0; i < 16; ++i) {
    int idx = base + i * 256 + t;
    if (idx < nseg) sum += cnt[idx];
  }
  s[t] = sum;
  __syncthreads();
  for (int st = 128; st > 0; st >>= 1) {
    if (t < st) s[t] += s[t + st];
    __syncthreads();
  }
  if (t == 0) blksum[b] = s[0];
}

__global__ void k_scan_top(int* __restrict__ blksum, int nblk, int* __restrict__ off,
                           int nseg, int E) {
  if (threadIdx.x == 0 && blockIdx.x == 0) {
    int run = 0;
    for (int b = 0; b < nblk; ++b) { int v = blksum[b]; blksum[b] = run; run += v; }
    off[nseg] = E;
  }
}

__global__ __launch_bounds__(256) void k_scan_write(const int* __restrict__ cnt,
                                                    const int* __restrict__ blksum,
                                                    int* __restrict__ off, int nseg) {
  __shared__ int s[256];
  int b = blockIdx.x, t = threadIdx.x;
  int base = b * SCAN_CHUNK + t * 16;
  int v[16];
  int sum = 0;
#pragma unroll
  for (int i = 0; i < 16; ++i) {
    int idx = base + i;
    v[i] = (idx < nseg) ? cnt[idx] : 0;
    sum += v[i];
  }
  s[t] = sum;
  __syncthreads();
  for (int st = 1; st < 256; st <<= 1) {
    int add = (t >= st) ? s[t - st] : 0;
    __syncthreads();
    s[t] += add;
    __syncthreads();
  }
  int run = blksum[b] + s[t] - sum;
#pragma unroll
  for (int i = 0; i < 16; ++i) {
    int idx = base + i;
    if (idx < nseg) off[idx] = run;
    run += v[i];
  }
}

__global__ __launch_bounds__(256) void k_scatter(const int* __restrict__ ei,
                                                 const int* __restrict__ et,
                                                 const int* __restrict__ off,
                                                 int* __restrict__ fill,
                                                 int* __restrict__ sorted, int E) {
  int e = blockIdx.x * 256 + threadIdx.x;
  if (e >= E) return;
  int src = ei[e], dst = ei[E + e];
  int seg = dst * 8 + et[e];
  int pos = off[seg] + atomicAdd(&fill[seg], 1);
  sorted[pos] = src;
}

static __device__ __forceinline__ void add8(float* a, uint4 v) {
  a[0] += bflo(v.x); a[1] += bfhi(v.x);
  a[2] += bflo(v.y); a[3] += bfhi(v.y);
  a[4] += bflo(v.z); a[5] += bfhi(v.z);
  a[6] += bflo(v.w); a[7] += bfhi(v.w);
}

// ---- aggregation: mean of h[src] per (dst,rel) segment -> Acat[dst][128 + r*128 : +128]
// 8 segments per wave, 8 lanes per segment (32B each), 2-edge unroll:
// 16 independent gather streams per wave for latency hiding.
__global__ __launch_bounds__(256) void k_agg(const int* __restrict__ off,
                                             const int* __restrict__ sorted,
                                             u16* acat, int nseg) {
  int wave = threadIdx.x >> 6, lane = threadIdx.x & 63;
  int sub = lane >> 3, oct = lane & 7;
  int seg = blockIdx.x * 32 + wave * 8 + sub;
  if (seg >= nseg) return;
  int s = off[seg], e = off[seg + 1];
  float a[16];
#pragma unroll
  for (int i = 0; i < 16; ++i) a[i] = 0.f;
  int j = s;
  for (; j + 2 <= e; j += 2) {
    int s0 = sorted[j], s1 = sorted[j + 1];
    const uint4* p0 = (const uint4*)(acat + (size_t)s0 * KCAT + oct * 16);
    const uint4* p1 = (const uint4*)(acat + (size_t)s1 * KCAT + oct * 16);
    uint4 v0 = p0[0], v0b = p0[1];
    uint4 v1 = p1[0], v1b = p1[1];
    add8(a, v0); add8(a + 8, v0b);
    add8(a, v1); add8(a + 8, v1b);
  }
  if (j < e) {
    const uint4* p0 = (const uint4*)(acat + (size_t)sorted[j] * KCAT + oct * 16);
    uint4 v0 = p0[0], v0b = p0[1];
    add8(a, v0); add8(a + 8, v0b);
  }
  float norm = (e > s) ? 1.0f / (float)(e - s) : 0.f;
  uint4 w0, w1;
  w0.x = (u32)f2bf(a[0] * norm) | ((u32)f2bf(a[1] * norm) << 16);
  w0.y = (u32)f2bf(a[2] * norm) | ((u32)f2bf(a[3] * norm) << 16);
  w0.z = (u32)f2bf(a[4] * norm) | ((u32)f2bf(a[5] * norm) << 16);
  w0.w = (u32)f2bf(a[6] * norm) | ((u32)f2bf(a[7] * norm) << 16);
  w1.x = (u32)f2bf(a[8] * norm) | ((u32)f2bf(a[9] * norm) << 16);
  w1.y = (u32)f2bf(a[10] * norm) | ((u32)f2bf(a[11] * norm) << 16);
  w1.z = (u32)f2bf(a[12] * norm) | ((u32)f2bf(a[13] * norm) << 16);
  w1.w = (u32)f2bf(a[14] * norm) | ((u32)f2bf(a[15] * norm) << 16);
  int dst = seg >> 3, r = seg & 7;
  uint4* outp = (uint4*)(acat + (size_t)dst * KCAT + DD + r * DD + oct * 16);
  outp[0] = w0;
  outp[1] = w1;
}

// ---- fused GEMM: out[row] = relu( Acat[row][0:1152] @ Wcat(1152x128) + bias )
// 128 rows/block, 8 waves. B k-tiles (32KB) double-buffered in LDS via async
// global_load_lds (wt is pre-swizzled so linear staging yields the swizzled layout).
// One barrier per k-tile; its implicit vmcnt(0) drain is the load-completion wait.
// LAST=false: write bf16 h_next into Acat[row][0:128] (blocks touch only own rows).
// LAST=true: write f32 to d_out.
template <bool LAST>
__global__ __launch_bounds__(512) void k_gemm(u16* acat, const uint4* __restrict__ wt,
                                              const float* __restrict__ bias,
                                              float* __restrict__ dout, int M) {
  __shared__ uint4 ldsB[2][2048];  // 2 x 32KB
  int tid = threadIdx.x, wave = tid >> 6, lane = tid & 63;
  int rowbase = blockIdx.x * 128 + wave * 16;
  int arow = rowbase + (lane & 15);
  int arc = arow < M ? arow : M - 1;
  int klane = (lane >> 4) << 3;
  f32x4 acc[8];
#pragma unroll
  for (int c = 0; c < 8; ++c) acc[c] = (f32x4)0.f;

#define STAGE(KT, BUF)                                                                   \
  do {                                                                                   \
    const uint4* gsrc = wt + (size_t)(KT) * 2048;                                        \
    _Pragma("unroll") for (int i_ = 0; i_ < 4; ++i_) {                                   \
      int cid_ = i_ * 512 + tid;                                                         \
      __builtin_amdgcn_global_load_lds(                                                  \
          (const __attribute__((address_space(1))) uint4*)(gsrc + cid_),                 \
          (__attribute__((address_space(3))) uint4*)&ldsB[BUF][cid_], 16, 0, 0);         \
    }                                                                                    \
  } while (0)

  STAGE(0, 0);
  for (int kt = 0; kt < NKT; ++kt) {
    int cur = kt & 1;
    __syncthreads();  // drains vmcnt -> buf[cur] staged; syncs reads of buf[cur^1]
    if (kt + 1 < NKT) STAGE(kt + 1, cur ^ 1);
#pragma unroll
    for (int kc = 0; kc < 4; ++kc) {
      short8 a = *(const short8*)(acat + (size_t)arc * KCAT + kt * DD + kc * 32 + klane);
      int chunk = kc * 4 + (lane >> 4);
#pragma unroll
      for (int c = 0; c < 8; ++c) {
        int col = c * 16 + (lane & 15);
        const short8* bp = (const short8*)&ldsB[cur][col * 16 + (chunk ^ (col & 7))];
        acc[c] = __builtin_amdgcn_mfma_f32_16x16x32_bf16(a, *bp, acc[c], 0, 0, 0);
      }
    }
  }
#undef STAGE

  int crow0 = rowbase + ((lane >> 4) << 2);
  int ccol = lane & 15;
#pragma unroll
  for (int c = 0; c < 8; ++c) {
    int col = c * 16 + ccol;
    float bv = bias[col];
#pragma unroll
    for (int i = 0; i < 4; ++i) {
      int row = crow0 + i;
      if (row < M) {
        float v = fmaxf(acc[c][i] + bv, 0.f);
        if (LAST) dout[(size_t)row * DD + col] = v;
        else acat[(size_t)row * KCAT + col] = f2bf(v);
      }
    }
  }
}

extern "C" void kernel_launch(void* const* d_in, const int* in_sizes, int n_in,
                              void* d_out, int out_size, void* d_ws, size_t ws_size,
                              hipStream_t stream) {
  const int* x = (const int*)d_in[0];
  const int* ei = (const int*)d_in[1];
  const int* et = (const int*)d_in[2];
  const float* emb = (const float*)d_in[3];
  const float* W = (const float*)d_in[4];
  const float* root = (const float*)d_in[5];
  const float* bias = (const float*)d_in[6];

  const int N = in_sizes[0];
  const int E = in_sizes[2];
  const int NSEG = N * RREL;

  size_t o = 0;
  auto al = [&](size_t b) { size_t r = o; o = (o + b + 255) & ~(size_t)255; return r; };
  size_t off_o = al(((size_t)NSEG + 1) * 4);
  size_t cnt_o = al((size_t)NSEG * 4);
  size_t fill_o = al((size_t)NSEG * 4);
  size_t sorted_o = al((size_t)E * 4);
  size_t blk_o = al(4096);
  size_t wt_o = al((size_t)2 * NKT * 2048 * 16);
  size_t acat_o = al((size_t)N * KCAT * 2);
  (void)acat_o;

  char* ws = (char*)d_ws;
  int* off = (int*)(ws + off_o);
  int* cnt = (int*)(ws + cnt_o);
  int* fill = (int*)(ws + fill_o);
  int* sorted = (int*)(ws + sorted_o);
  int* blks = (int*)(ws + blk_o);
  uint4* wt = (uint4*)(ws + wt_o);
  u16* acat = (u16*)(ws + acat_o);
  float* outf = (float*)d_out;

  // ---- prep
  k_convw<<<(2 * NKT * 2048 + 255) / 256, 256, 0, stream>>>(W, root, wt);
  k_gather<<<(N * 16 + 255) / 256, 256, 0, stream>>>(x, emb, acat, N);
  hipMemsetAsync(cnt, 0, (size_t)NSEG * 4, stream);
  hipMemsetAsync(fill, 0, (size_t)NSEG * 4, stream);
  k_hist<<<(E + 255) / 256, 256, 0, stream>>>(ei, et, cnt, E);
  int nblk = (NSEG + SCAN_CHUNK - 1) / SCAN_CHUNK;
  k_scan_reduce<<<nblk, 256, 0, stream>>>(cnt, blks, NSEG);
  k_scan_top<<<1, 64, 0, stream>>>(blks, nblk, off, NSEG, E);
  k_scan_write<<<nblk, 256, 0, stream>>>(cnt, blks, off, NSEG);
  k_scatter<<<(E + 255) / 256, 256, 0, stream>>>(ei, et, off, fill, sorted, E);

  // ---- layers: agg (mean into Acat) then fused GEMM (root+rels+bias+relu)
  int gx = (N + 127) / 128;
  k_agg<<<(NSEG + 31) / 32, 256, 0, stream>>>(off, sorted, acat, NSEG);
  k_gemm<false><<<gx, 512, 0, stream>>>(acat, wt, bias, nullptr, N);
  k_agg<<<(NSEG + 31) / 32, 256, 0, stream>>>(off, sorted, acat, NSEG);
  k_gemm<true><<<gx, 512, 0, stream>>>(acat, wt + (size_t)NKT * 2048, bias + DD, outf, N);
}